// Round 17
// baseline (78.692 us; speedup 1.0000x reference)
//
#include <hip/hip_runtime.h>
#include <hip/hip_bf16.h>
#include <math.h>

typedef __attribute__((ext_vector_type(8))) short bf16x8;
typedef __attribute__((ext_vector_type(4))) float f32x4;

#define B_ 4
#define C_ 128
#define LOG2E 1.4426950408889634f

// ---- workspace layout (r16, proven) ----
#define XT1_B   0ull                      // 4 MB
#define XTT1_B  4194304ull                // 4 MB
#define O1P_B   8388608ull                // bf16 [4][4][128][4096]  16 MB
#define ML1_B   25165824ull               // f32  [4][4][4096][2]    512 KB
#define TAIL_B  25690112ull
#define XT2_B   (TAIL_B + 0ull)           // bf16 [4][1024][128]     1 MB
#define XTT2_B  (TAIL_B + 1048576ull)     // bf16 [4][128][1024]     1 MB
#define XT4_B   (TAIL_B + 2097152ull)     // bf16 [4][256][128]      256 KB
#define XTT4_B  (TAIL_B + 2359296ull)     // bf16 [4][128][256]      256 KB
#define A2P_B   (TAIL_B + 2621440ull)     // bf16 [8][4][128][1024]  8 MB
#define ML2_B   (TAIL_B + 11010048ull)    // f32  [8][4][1024][2]    256 KB
#define A4P_B   (TAIL_B + 11272192ull)    // bf16 [2][4][128][256]   512 KB
#define ML4_B   (TAIL_B + 11796480ull)    // f32  [2][4][256][2]     16 KB
// total = 37,502,976 B (ws >= 44.3 MB proven in r9/r12)

__device__ __forceinline__ float ex2(float x) { return __builtin_amdgcn_exp2f(x); }

__device__ __forceinline__ unsigned short f2bf(float f) {
    unsigned int u = __builtin_bit_cast(unsigned int, f);
    return (unsigned short)((u + 0x7FFFu + ((u >> 16) & 1u)) >> 16);
}
__device__ __forceinline__ float bf2f(unsigned short u) {
    unsigned int x = ((unsigned int)u) << 16;
    return __builtin_bit_cast(float, x);
}
__device__ __forceinline__ unsigned int pkbf(float lo, float hi) {
    union { __hip_bfloat162 h; unsigned int u; } c;
    c.h = __float22bfloat162_rn(make_float2(lo, hi));   // v_cvt_pk_bf16_f32
    return c.u;
}
__device__ __forceinline__ void gload_lds16(const void* g, void* l) {
    __builtin_amdgcn_global_load_lds(
        (const __attribute__((address_space(1))) unsigned int*)g,
        (__attribute__((address_space(3))) unsigned int*)l, 16, 0, 0);
}

// ---------------- fused pool: x[B][C][64][64] -> {xt,xtT} for scales 1,2,4
__global__ __launch_bounds__(256) void pool_all(const float* __restrict__ x,
                                                unsigned short* __restrict__ xt1,
                                                unsigned short* __restrict__ xtT1,
                                                unsigned short* __restrict__ xt2,
                                                unsigned short* __restrict__ xtT2,
                                                unsigned short* __restrict__ xt4,
                                                unsigned short* __restrict__ xtT4) {
    constexpr int RS = 257;
    __shared__ float lds[32 * RS];
    const int hp4 = blockIdx.x;
    const int c0  = blockIdx.y * 32;
    const int b   = blockIdx.z;
    const int t   = threadIdx.x;

    #pragma unroll
    for (int i = 0; i < 8; ++i) {
        int e4 = (i * 256 + t) * 4;
        int ci = e4 >> 8, rem = e4 & 255;
        float4 v = *reinterpret_cast<const float4*>(
            &x[((size_t)(b * C_ + c0 + ci) * 64 + (hp4 * 4 + (rem >> 6))) * 64 + (rem & 63)]);
        *reinterpret_cast<float4*>(&lds[ci * RS + rem]) = v;
    }
    __syncthreads();

    // scale 1, pair-packed stores
    #pragma unroll
    for (int i = 0; i < 16; ++i) {
        int p  = i * 256 + t;
        int c2 = p & 15;
        int pos = p >> 4;
        unsigned int v = pkbf(lds[(2 * c2) * RS + pos], lds[(2 * c2 + 1) * RS + pos]);
        *reinterpret_cast<unsigned int*>(
            &xt1[((size_t)b * 4096 + hp4 * 256 + pos) * C_ + c0 + 2 * c2]) = v;
    }
    #pragma unroll
    for (int i = 0; i < 16; ++i) {
        int p  = i * 256 + t;
        int p2 = p & 127;
        int ci = p >> 7;
        unsigned int v = pkbf(lds[ci * RS + 2 * p2], lds[ci * RS + 2 * p2 + 1]);
        *reinterpret_cast<unsigned int*>(
            &xtT1[((size_t)(b * C_ + c0 + ci)) * 4096 + hp4 * 256 + 2 * p2]) = v;
    }
    // scale 2
    #pragma unroll
    for (int i = 0; i < 8; ++i) {
        int v = i * 256 + t;
        int ci = v & 31, pz = v >> 5;
        int r2 = pz >> 5, w2 = pz & 31;
        float s = lds[ci * RS + (2*r2)*64 + 2*w2]     + lds[ci * RS + (2*r2)*64 + 2*w2 + 1]
                + lds[ci * RS + (2*r2+1)*64 + 2*w2]   + lds[ci * RS + (2*r2+1)*64 + 2*w2 + 1];
        xt2[((size_t)b * 1024 + (hp4*2 + r2)*32 + w2) * C_ + c0 + ci] = f2bf(s * 0.25f);
    }
    #pragma unroll
    for (int i = 0; i < 8; ++i) {
        int v = i * 256 + t;
        int pz = v & 63, ci = v >> 6;
        int r2 = pz >> 5, w2 = pz & 31;
        float s = lds[ci * RS + (2*r2)*64 + 2*w2]     + lds[ci * RS + (2*r2)*64 + 2*w2 + 1]
                + lds[ci * RS + (2*r2+1)*64 + 2*w2]   + lds[ci * RS + (2*r2+1)*64 + 2*w2 + 1];
        xtT2[((size_t)(b * C_ + c0 + ci)) * 1024 + (hp4*2 + r2)*32 + w2] = f2bf(s * 0.25f);
    }
    // scale 4
    #pragma unroll
    for (int i = 0; i < 2; ++i) {
        int v = i * 256 + t;
        int ci = v & 31, w4 = v >> 5;
        float s = 0.f;
        #pragma unroll
        for (int r = 0; r < 4; ++r)
            #pragma unroll
            for (int j = 0; j < 4; ++j) s += lds[ci * RS + r*64 + w4*4 + j];
        xt4[((size_t)b * 256 + hp4*16 + w4) * C_ + c0 + ci] = f2bf(s * 0.0625f);
    }
    #pragma unroll
    for (int i = 0; i < 2; ++i) {
        int v = i * 256 + t;
        int w4 = v & 15, ci = v >> 4;
        float s = 0.f;
        #pragma unroll
        for (int r = 0; r < 4; ++r)
            #pragma unroll
            for (int j = 0; j < 4; ++j) s += lds[ci * RS + r*64 + w4*4 + j];
        xtT4[((size_t)(b * C_ + c0 + ci)) * 256 + hp4*16 + w4] = f2bf(s * 0.0625f);
    }
}

// ---------------- MFMA flash attention body: r9's K-dbuf + V-SINGLE buffer
// (48 KB LDS -> 3 blocks/CU) with the default register budget (no min-3
// launch_bounds — r9's only defect was the forced VGPR=84 spill).
template<int N, int SPLIT>
__device__ __forceinline__ void attn_body(const unsigned short* __restrict__ xt,
                                          const unsigned short* __restrict__ xtT,
                                          unsigned short* __restrict__ op,
                                          float* __restrict__ ml,
                                          const int bid, char* lds) {
    constexpr int LOG2S = (SPLIT == 2) ? 1 : ((SPLIT == 4) ? 2 : 3);
    constexpr int QB = N / 128;
    constexpr int W2 = QB * SPLIT / 2;
    constexpr int NT = N / SPLIT / 64;
    static_assert(NT >= 2 && (NT & 1) == 0, "even NT >= 2 required");
    const int xcd   = bid & 7;
    const int b     = xcd >> 1;                 // batch pinned to XCD pair (L2 locality)
    const int wi    = (xcd & 1) * W2 + (bid >> 3);
    const int split = wi & (SPLIT - 1);
    const int qx    = wi >> LOG2S;
    const int n0    = qx * 128;
    const int m_beg = split * (N / SPLIT);

    const int tid = threadIdx.x;
    const int w = tid >> 6, lane = tid & 63;
    const int g = lane >> 4, rho = lane & 15;

    const char* xb  = (const char*)(xt  + (size_t)b * N * C_);
    const char* xtb = (const char*)(xtT + (size_t)b * C_ * N);

    bf16x8 qf[2][4];
    #pragma unroll
    for (int tt = 0; tt < 2; ++tt) {
        const char* qr = xb + (size_t)(n0 + w * 32 + tt * 16 + rho) * 256;
        #pragma unroll
        for (int kc = 0; kc < 4; ++kc) {
            bf16x8 raw = *(const bf16x8*)(qr + kc * 64 + g * 16);
            bf16x8 s;
            #pragma unroll
            for (int e = 0; e < 8; ++e)
                s[e] = (short)f2bf(bf2f((unsigned short)raw[e]) * LOG2E);
            qf[tt][kc] = s;
        }
    }

    int kOff[4], vOff[4];
    #pragma unroll
    for (int k = 0; k < 4; ++k) {
        int D = (w * 4 + k) * 1024 + lane * 16;
        int row = D >> 8, colb = D & 255;
        kOff[k] = row * 256 + (colb ^ ((row & 15) << 4));
        int c = D >> 7, cb2 = D & 127;
        vOff[k] = c * (2 * N) + (cb2 ^ ((c & 7) << 4));
    }
    int qkOff[4][4], pvOff[8][2];
    #pragma unroll
    for (int mb = 0; mb < 4; ++mb) {
        int rowm = ((mb >> 1) << 5) + ((mb & 1) << 2) + ((rho >> 2) << 3) + (rho & 3);
        int swz = (rowm & 15) << 4;
        #pragma unroll
        for (int kc = 0; kc < 4; ++kc)
            qkOff[mb][kc] = rowm * 256 + ((kc * 64 + g * 16) ^ swz);
    }
    #pragma unroll
    for (int cb = 0; cb < 8; ++cb) {
        int c = cb * 16 + rho;
        int vswz = (c & 7) << 4;
        #pragma unroll
        for (int ks = 0; ks < 2; ++ks)
            pvOff[cb][ks] = c * 128 + ((ks * 64 + g * 16) ^ vswz);
    }

    char* const KB0 = lds;
    char* const KB1 = lds + 16384;
    char* const VB  = lds + 32768;       // single 16 KB V buffer
    const char* kG = xb  + (size_t)m_beg * 256;
    const char* vG = xtb + (size_t)m_beg * 2;

    auto stageK = [&](char* dst, int tile) {
        const char* s = kG + (size_t)tile * (64 * 256);
        #pragma unroll
        for (int k = 0; k < 4; ++k) gload_lds16(s + kOff[k], dst + (w * 4 + k) * 1024);
    };
    auto stageV = [&](int tile) {
        const char* s = vG + (size_t)tile * (64 * 2);
        #pragma unroll
        for (int k = 0; k < 4; ++k) gload_lds16(s + vOff[k], VB + (w * 4 + k) * 1024);
    };

    f32x4 acc[2][8];
    #pragma unroll
    for (int tt = 0; tt < 2; ++tt)
        #pragma unroll
        for (int cb = 0; cb < 8; ++cb) acc[tt][cb] = (f32x4){0.f, 0.f, 0.f, 0.f};
    float m_run[2] = {-INFINITY, -INFINITY};
    float l_lane[2] = {0.f, 0.f};

    auto qkt = [&](const char* kb, f32x4 (&aS)[2][4]) {
        #pragma unroll
        for (int tt = 0; tt < 2; ++tt)
            #pragma unroll
            for (int mb = 0; mb < 4; ++mb) aS[tt][mb] = (f32x4){0.f, 0.f, 0.f, 0.f};
        #pragma unroll
        for (int mb = 0; mb < 4; ++mb)
            #pragma unroll
            for (int kc = 0; kc < 4; ++kc) {
                bf16x8 kf = *(const bf16x8*)(kb + qkOff[mb][kc]);
                aS[0][mb] = __builtin_amdgcn_mfma_f32_16x16x32_bf16(kf, qf[0][kc], aS[0][mb], 0, 0, 0);
                aS[1][mb] = __builtin_amdgcn_mfma_f32_16x16x32_bf16(kf, qf[1][kc], aS[1][mb], 0, 0, 0);
            }
    };

    auto smpv = [&](f32x4 (&aS)[2][4]) {
        bf16x8 pb[2][2];
        #pragma unroll
        for (int tt = 0; tt < 2; ++tt) {
            float tm = aS[tt][0][0];
            #pragma unroll
            for (int mb = 0; mb < 4; ++mb)
                #pragma unroll
                for (int r = 0; r < 4; ++r) tm = fmaxf(tm, aS[tt][mb][r]);
            tm = fmaxf(tm, __shfl_xor(tm, 16));
            tm = fmaxf(tm, __shfl_xor(tm, 32));
            if (!__all(tm <= m_run[tt] + 6.0f)) {
                float nm = fmaxf(m_run[tt], tm);
                float sc = ex2(m_run[tt] - nm);
                l_lane[tt] *= sc;
                m_run[tt] = nm;
                #pragma unroll
                for (int cb = 0; cb < 8; ++cb) {
                    acc[tt][cb][0] *= sc; acc[tt][cb][1] *= sc;
                    acc[tt][cb][2] *= sc; acc[tt][cb][3] *= sc;
                }
            }
            float p[4][4];
            #pragma unroll
            for (int mb = 0; mb < 4; ++mb)
                #pragma unroll
                for (int r = 0; r < 4; ++r) {
                    p[mb][r] = ex2(aS[tt][mb][r] - m_run[tt]);
                    l_lane[tt] += p[mb][r];
                }
            #pragma unroll
            for (int ks = 0; ks < 2; ++ks) {
                union { bf16x8 v; unsigned int u[4]; } pk;
                pk.u[0] = pkbf(p[2 * ks][0],     p[2 * ks][1]);
                pk.u[1] = pkbf(p[2 * ks][2],     p[2 * ks][3]);
                pk.u[2] = pkbf(p[2 * ks + 1][0], p[2 * ks + 1][1]);
                pk.u[3] = pkbf(p[2 * ks + 1][2], p[2 * ks + 1][3]);
                pb[tt][ks] = pk.v;
            }
        }
        #pragma unroll
        for (int cb = 0; cb < 8; ++cb)
            #pragma unroll
            for (int ks = 0; ks < 2; ++ks) {
                bf16x8 vf = *(const bf16x8*)(VB + pvOff[cb][ks]);
                acc[0][cb] = __builtin_amdgcn_mfma_f32_16x16x32_bf16(vf, pb[0][ks], acc[0][cb], 0, 0, 0);
                acc[1][cb] = __builtin_amdgcn_mfma_f32_16x16x32_bf16(vf, pb[1][ks], acc[1][cb], 0, 0, 0);
            }
    };

    f32x4 accA[2][4], accB[2][4];

    // prologue: K0, V0, K1 staged (12 loads out); ledger: 8 / 4,4 / 0,0
    stageK(KB0, 0); stageV(0); stageK(KB1, 1);
    asm volatile("s_waitcnt vmcnt(8)" ::: "memory");    // K0 complete
    __builtin_amdgcn_s_barrier();
    qkt(KB0, accA);
    __builtin_amdgcn_s_barrier();
    if constexpr (NT > 2) stageK(KB0, 2);

    #pragma unroll 1
    for (int j = 0; j + 3 < NT; j += 2) {
        asm volatile("s_waitcnt vmcnt(4)" ::: "memory");   // K(j+1), V(j) done
        __builtin_amdgcn_s_barrier();
        qkt(KB1, accB);
        smpv(accA);
        __builtin_amdgcn_s_barrier();
        stageV(j + 1);
        stageK(KB1, j + 3);
        asm volatile("s_waitcnt vmcnt(4)" ::: "memory");   // K(j+2), V(j+1) done
        __builtin_amdgcn_s_barrier();
        qkt(KB0, accA);
        smpv(accB);
        __builtin_amdgcn_s_barrier();
        stageV(j + 2);
        if (j + 4 < NT) stageK(KB0, j + 4);
    }
    asm volatile("s_waitcnt vmcnt(0)" ::: "memory");
    __builtin_amdgcn_s_barrier();
    qkt(KB1, accB);
    smpv(accA);
    __builtin_amdgcn_s_barrier();
    stageV(NT - 1);
    asm volatile("s_waitcnt vmcnt(0)" ::: "memory");
    __builtin_amdgcn_s_barrier();
    smpv(accB);

    #pragma unroll
    for (int tt = 0; tt < 2; ++tt) {
        l_lane[tt] += __shfl_xor(l_lane[tt], 16);
        l_lane[tt] += __shfl_xor(l_lane[tt], 32);
        const int n = n0 + w * 32 + tt * 16 + rho;
        #pragma unroll
        for (int cb = 0; cb < 8; ++cb)
            #pragma unroll
            for (int r = 0; r < 4; ++r)
                op[((size_t)(split * B_ + b) * C_ + cb * 16 + g * 4 + r) * N + n] = f2bf(acc[tt][cb][r]);
        if (g == 0) {
            ml[((size_t)(split * B_ + b) * N + n) * 2 + 0] = m_run[tt];
            ml[((size_t)(split * B_ + b) * N + n) * 2 + 1] = l_lane[tt];
        }
    }
}

// ONE launch for all three scales; smalls first and SHORT (r14/r16 shape).
// 48 KB LDS per block -> 3 blocks/CU resident.
__global__ __launch_bounds__(256, 2) void attn_fused(const unsigned short* __restrict__ xt1,
                                                     const unsigned short* __restrict__ xtT1,
                                                     unsigned short* __restrict__ o1p,
                                                     float* __restrict__ ml1,
                                                     const unsigned short* __restrict__ xt2,
                                                     const unsigned short* __restrict__ xtT2,
                                                     unsigned short* __restrict__ a2p,
                                                     float* __restrict__ ml2,
                                                     const unsigned short* __restrict__ xt4,
                                                     const unsigned short* __restrict__ xtT4,
                                                     unsigned short* __restrict__ a4p,
                                                     float* __restrict__ ml4) {
    __shared__ char lds[49152];
    const int bid = (int)blockIdx.x;
    if (bid < 256)
        attn_body<1024, 8>(xt2, xtT2, a2p, ml2, bid, lds);
    else if (bid < 272)
        attn_body<256, 2>(xt4, xtT4, a4p, ml4, bid - 256, lds);
    else
        attn_body<4096, 4>(xt1, xtT1, o1p, ml1, bid - 272, lds);
}

// ---------------- fused merge + upsample + scale-1 merge (r16, proven).
__global__ __launch_bounds__(256) void combine2(float* __restrict__ out,
                                                const unsigned short* __restrict__ o1p,
                                                const float* __restrict__ ml1,
                                                const unsigned short* __restrict__ a2p,
                                                const float* __restrict__ ml2,
                                                const unsigned short* __restrict__ a4p,
                                                const float* __restrict__ ml4) {
    __shared__ float a2s[1024];
    __shared__ float a4s[256];
    const int bc = (int)blockIdx.x;
    const int b  = bc >> 7;
    const int c  = bc & 127;
    const int t  = threadIdx.x;

    #pragma unroll
    for (int i = 0; i < 4; ++i) {
        int n = i * 256 + t;
        float M = -INFINITY;
        #pragma unroll
        for (int s = 0; s < 8; ++s) M = fmaxf(M, ml2[((s * 4 + b) * 1024 + n) * 2]);
        float L = 0.f, O = 0.f;
        #pragma unroll
        for (int s = 0; s < 8; ++s) {
            float wgt = ex2(ml2[((s * 4 + b) * 1024 + n) * 2] - M);
            L += ml2[((s * 4 + b) * 1024 + n) * 2 + 1] * wgt;
            O += bf2f(a2p[((size_t)((s * 4 + b) * 128 + c)) * 1024 + n]) * wgt;
        }
        a2s[n] = O / L;
    }
    {
        int n = t;
        float m0 = ml4[((0 * 4 + b) * 256 + n) * 2], l0 = ml4[((0 * 4 + b) * 256 + n) * 2 + 1];
        float m1 = ml4[((1 * 4 + b) * 256 + n) * 2], l1 = ml4[((1 * 4 + b) * 256 + n) * 2 + 1];
        float M  = fmaxf(m0, m1);
        float w0 = ex2(m0 - M), w1 = ex2(m1 - M);
        float O  = bf2f(a4p[((size_t)((0 * 4 + b) * 128 + c)) * 256 + n]) * w0
                 + bf2f(a4p[((size_t)((1 * 4 + b) * 128 + c)) * 256 + n]) * w1;
        a4s[n] = O / (l0 * w0 + l1 * w1);
    }
    __syncthreads();

    #pragma unroll
    for (int i = 0; i < 16; ++i) {
        int e = i * 256 + t;
        int h = e >> 6, w = e & 63;
        float M = -INFINITY;
        #pragma unroll
        for (int s = 0; s < 4; ++s) M = fmaxf(M, ml1[((size_t)(s * 4 + b) * 4096 + e) * 2]);
        float num = 0.f, den = 0.f;
        #pragma unroll
        for (int s = 0; s < 4; ++s) {
            float wgt = ex2(ml1[((size_t)(s * 4 + b) * 4096 + e) * 2] - M);
            den += ml1[((size_t)(s * 4 + b) * 4096 + e) * 2 + 1] * wgt;
            num += bf2f(o1p[((size_t)(s * 512 + bc)) * 4096 + e]) * wgt;
        }
        float v = num / den;
        {
            float sh = (h + 0.5f) * 0.5f - 0.5f;
            float sw = (w + 0.5f) * 0.5f - 0.5f;
            int h0 = (int)floorf(sh); float fh = sh - (float)h0;
            int w0 = (int)floorf(sw); float fw = sw - (float)w0;
            int h0c = max(h0, 0), h1c = min(h0 + 1, 31);
            int w0c = max(w0, 0), w1c = min(w0 + 1, 31);
            float v00 = a2s[h0c * 32 + w0c], v01 = a2s[h0c * 32 + w1c];
            float v10 = a2s[h1c * 32 + w0c], v11 = a2s[h1c * 32 + w1c];
            v += (1.f - fh) * ((1.f - fw) * v00 + fw * v01)
               +        fh  * ((1.f - fw) * v10 + fw * v11);
        }
        {
            float sh = (h + 0.5f) * 0.25f - 0.5f;
            float sw = (w + 0.5f) * 0.25f - 0.5f;
            int h0 = (int)floorf(sh); float fh = sh - (float)h0;
            int w0 = (int)floorf(sw); float fw = sw - (float)w0;
            int h0c = max(h0, 0), h1c = min(h0 + 1, 15);
            int w0c = max(w0, 0), w1c = min(w0 + 1, 15);
            float v00 = a4s[h0c * 16 + w0c], v01 = a4s[h0c * 16 + w1c];
            float v10 = a4s[h1c * 16 + w0c], v11 = a4s[h1c * 16 + w1c];
            v += (1.f - fh) * ((1.f - fw) * v00 + fw * v01)
               +        fh  * ((1.f - fw) * v10 + fw * v11);
        }
        out[(size_t)bc * 4096 + e] = v;
    }
}

extern "C" void kernel_launch(void* const* d_in, const int* in_sizes, int n_in,
                              void* d_out, int out_size, void* d_ws, size_t ws_size,
                              hipStream_t stream) {
    const float* x = (const float*)d_in[0];
    float* out = (float*)d_out;
    char* ws = (char*)d_ws;
    unsigned short* xt1  = (unsigned short*)(ws + XT1_B);
    unsigned short* xtT1 = (unsigned short*)(ws + XTT1_B);
    unsigned short* o1p  = (unsigned short*)(ws + O1P_B);
    float*          ml1  = (float*)(ws + ML1_B);
    unsigned short* xt2  = (unsigned short*)(ws + XT2_B);
    unsigned short* xtT2 = (unsigned short*)(ws + XTT2_B);
    unsigned short* xt4  = (unsigned short*)(ws + XT4_B);
    unsigned short* xtT4 = (unsigned short*)(ws + XTT4_B);
    unsigned short* a2p  = (unsigned short*)(ws + A2P_B);
    float*          ml2  = (float*)(ws + ML2_B);
    unsigned short* a4p  = (unsigned short*)(ws + A4P_B);
    float*          ml4  = (float*)(ws + ML4_B);

    pool_all<<<dim3(16, 4, B_), 256, 0, stream>>>(x, xt1, xtT1, xt2, xtT2, xt4, xtT4);
    attn_fused<<<784, 256, 0, stream>>>(xt1, xtT1, o1p, ml1,
                                        xt2, xtT2, a2p, ml2,
                                        xt4, xtT4, a4p, ml4);
    combine2<<<512, 256, 0, stream>>>(out, o1p, ml1, a2p, ml2, a4p, ml4);
}

// Round 18
// 75.030 us; speedup vs baseline: 1.0488x; 1.0488x over previous
//
#include <hip/hip_runtime.h>
#include <hip/hip_bf16.h>
#include <math.h>

typedef __attribute__((ext_vector_type(8))) short bf16x8;
typedef __attribute__((ext_vector_type(4))) float f32x4;

#define B_ 4
#define C_ 128
#define LOG2E 1.4426950408889634f

// ---- workspace layout (r16, proven) ----
#define XT1_B   0ull                      // 4 MB
#define XTT1_B  4194304ull                // 4 MB
#define O1P_B   8388608ull                // bf16 [4][4][128][4096]  16 MB
#define ML1_B   25165824ull               // f32  [4][4][4096][2]    512 KB
#define TAIL_B  25690112ull
#define XT2_B   (TAIL_B + 0ull)           // bf16 [4][1024][128]     1 MB
#define XTT2_B  (TAIL_B + 1048576ull)     // bf16 [4][128][1024]     1 MB
#define XT4_B   (TAIL_B + 2097152ull)     // bf16 [4][256][128]      256 KB
#define XTT4_B  (TAIL_B + 2359296ull)     // bf16 [4][128][256]      256 KB
#define A2P_B   (TAIL_B + 2621440ull)     // bf16 [8][4][128][1024]  8 MB
#define ML2_B   (TAIL_B + 11010048ull)    // f32  [8][4][1024][2]    256 KB
#define A4P_B   (TAIL_B + 11272192ull)    // bf16 [2][4][128][256]   512 KB
#define ML4_B   (TAIL_B + 11796480ull)    // f32  [2][4][256][2]     16 KB
// total = 37,502,976 B (ws >= 44.3 MB proven in r9/r12)

__device__ __forceinline__ float ex2(float x) { return __builtin_amdgcn_exp2f(x); }

__device__ __forceinline__ unsigned short f2bf(float f) {
    unsigned int u = __builtin_bit_cast(unsigned int, f);
    return (unsigned short)((u + 0x7FFFu + ((u >> 16) & 1u)) >> 16);
}
__device__ __forceinline__ float bf2f(unsigned short u) {
    unsigned int x = ((unsigned int)u) << 16;
    return __builtin_bit_cast(float, x);
}
__device__ __forceinline__ unsigned int pkbf(float lo, float hi) {
    union { __hip_bfloat162 h; unsigned int u; } c;
    c.h = __float22bfloat162_rn(make_float2(lo, hi));   // v_cvt_pk_bf16_f32
    return c.u;
}
__device__ __forceinline__ void gload_lds16(const void* g, void* l) {
    __builtin_amdgcn_global_load_lds(
        (const __attribute__((address_space(1))) unsigned int*)g,
        (__attribute__((address_space(3))) unsigned int*)l, 16, 0, 0);
}

// ---------------- fused pool: x[B][C][64][64] -> {xt,xtT} for scales 1,2,4
__global__ __launch_bounds__(256) void pool_all(const float* __restrict__ x,
                                                unsigned short* __restrict__ xt1,
                                                unsigned short* __restrict__ xtT1,
                                                unsigned short* __restrict__ xt2,
                                                unsigned short* __restrict__ xtT2,
                                                unsigned short* __restrict__ xt4,
                                                unsigned short* __restrict__ xtT4) {
    constexpr int RS = 257;
    __shared__ float lds[32 * RS];
    const int hp4 = blockIdx.x;
    const int c0  = blockIdx.y * 32;
    const int b   = blockIdx.z;
    const int t   = threadIdx.x;

    #pragma unroll
    for (int i = 0; i < 8; ++i) {
        int e4 = (i * 256 + t) * 4;
        int ci = e4 >> 8, rem = e4 & 255;
        float4 v = *reinterpret_cast<const float4*>(
            &x[((size_t)(b * C_ + c0 + ci) * 64 + (hp4 * 4 + (rem >> 6))) * 64 + (rem & 63)]);
        *reinterpret_cast<float4*>(&lds[ci * RS + rem]) = v;
    }
    __syncthreads();

    // scale 1, pair-packed stores
    #pragma unroll
    for (int i = 0; i < 16; ++i) {
        int p  = i * 256 + t;
        int c2 = p & 15;
        int pos = p >> 4;
        unsigned int v = pkbf(lds[(2 * c2) * RS + pos], lds[(2 * c2 + 1) * RS + pos]);
        *reinterpret_cast<unsigned int*>(
            &xt1[((size_t)b * 4096 + hp4 * 256 + pos) * C_ + c0 + 2 * c2]) = v;
    }
    #pragma unroll
    for (int i = 0; i < 16; ++i) {
        int p  = i * 256 + t;
        int p2 = p & 127;
        int ci = p >> 7;
        unsigned int v = pkbf(lds[ci * RS + 2 * p2], lds[ci * RS + 2 * p2 + 1]);
        *reinterpret_cast<unsigned int*>(
            &xtT1[((size_t)(b * C_ + c0 + ci)) * 4096 + hp4 * 256 + 2 * p2]) = v;
    }
    // scale 2
    #pragma unroll
    for (int i = 0; i < 8; ++i) {
        int v = i * 256 + t;
        int ci = v & 31, pz = v >> 5;
        int r2 = pz >> 5, w2 = pz & 31;
        float s = lds[ci * RS + (2*r2)*64 + 2*w2]     + lds[ci * RS + (2*r2)*64 + 2*w2 + 1]
                + lds[ci * RS + (2*r2+1)*64 + 2*w2]   + lds[ci * RS + (2*r2+1)*64 + 2*w2 + 1];
        xt2[((size_t)b * 1024 + (hp4*2 + r2)*32 + w2) * C_ + c0 + ci] = f2bf(s * 0.25f);
    }
    #pragma unroll
    for (int i = 0; i < 8; ++i) {
        int v = i * 256 + t;
        int pz = v & 63, ci = v >> 6;
        int r2 = pz >> 5, w2 = pz & 31;
        float s = lds[ci * RS + (2*r2)*64 + 2*w2]     + lds[ci * RS + (2*r2)*64 + 2*w2 + 1]
                + lds[ci * RS + (2*r2+1)*64 + 2*w2]   + lds[ci * RS + (2*r2+1)*64 + 2*w2 + 1];
        xtT2[((size_t)(b * C_ + c0 + ci)) * 1024 + (hp4*2 + r2)*32 + w2] = f2bf(s * 0.25f);
    }
    // scale 4
    #pragma unroll
    for (int i = 0; i < 2; ++i) {
        int v = i * 256 + t;
        int ci = v & 31, w4 = v >> 5;
        float s = 0.f;
        #pragma unroll
        for (int r = 0; r < 4; ++r)
            #pragma unroll
            for (int j = 0; j < 4; ++j) s += lds[ci * RS + r*64 + w4*4 + j];
        xt4[((size_t)b * 256 + hp4*16 + w4) * C_ + c0 + ci] = f2bf(s * 0.0625f);
    }
    #pragma unroll
    for (int i = 0; i < 2; ++i) {
        int v = i * 256 + t;
        int w4 = v & 15, ci = v >> 4;
        float s = 0.f;
        #pragma unroll
        for (int r = 0; r < 4; ++r)
            #pragma unroll
            for (int j = 0; j < 4; ++j) s += lds[ci * RS + r*64 + w4*4 + j];
        xtT4[((size_t)(b * C_ + c0 + ci)) * 256 + hp4*16 + w4] = f2bf(s * 0.0625f);
    }
}

// ---------------- MFMA flash attention body (round-10/16, proven config).
// KVBLK=64, split K/V double buffers (4 x 16 KB), counted-vmcnt schedule.
template<int N, int SPLIT>
__device__ __forceinline__ void attn_body(const unsigned short* __restrict__ xt,
                                          const unsigned short* __restrict__ xtT,
                                          unsigned short* __restrict__ op,
                                          float* __restrict__ ml,
                                          const int bid, char* lds) {
    constexpr int LOG2S = (SPLIT == 2) ? 1 : ((SPLIT == 4) ? 2 : 3);
    constexpr int QB = N / 128;
    constexpr int W2 = QB * SPLIT / 2;
    constexpr int NT = N / SPLIT / 64;
    static_assert(NT >= 2 && (NT & 1) == 0, "even NT >= 2 required");
    const int xcd   = bid & 7;
    const int b     = xcd >> 1;                 // batch pinned to XCD pair (L2 locality)
    const int wi    = (xcd & 1) * W2 + (bid >> 3);
    const int split = wi & (SPLIT - 1);
    const int qx    = wi >> LOG2S;
    const int n0    = qx * 128;
    const int m_beg = split * (N / SPLIT);

    const int tid = threadIdx.x;
    const int w = tid >> 6, lane = tid & 63;
    const int g = lane >> 4, rho = lane & 15;

    const char* xb  = (const char*)(xt  + (size_t)b * N * C_);
    const char* xtb = (const char*)(xtT + (size_t)b * C_ * N);

    bf16x8 qf[2][4];
    #pragma unroll
    for (int tt = 0; tt < 2; ++tt) {
        const char* qr = xb + (size_t)(n0 + w * 32 + tt * 16 + rho) * 256;
        #pragma unroll
        for (int kc = 0; kc < 4; ++kc) {
            bf16x8 raw = *(const bf16x8*)(qr + kc * 64 + g * 16);
            bf16x8 s;
            #pragma unroll
            for (int e = 0; e < 8; ++e)
                s[e] = (short)f2bf(bf2f((unsigned short)raw[e]) * LOG2E);
            qf[tt][kc] = s;
        }
    }

    int kOff[4], vOff[4];
    #pragma unroll
    for (int k = 0; k < 4; ++k) {
        int D = (w * 4 + k) * 1024 + lane * 16;
        int row = D >> 8, colb = D & 255;
        kOff[k] = row * 256 + (colb ^ ((row & 15) << 4));
        int c = D >> 7, cb2 = D & 127;
        vOff[k] = c * (2 * N) + (cb2 ^ ((c & 7) << 4));
    }
    int qkOff[4][4], pvOff[8][2];
    #pragma unroll
    for (int mb = 0; mb < 4; ++mb) {
        int rowm = ((mb >> 1) << 5) + ((mb & 1) << 2) + ((rho >> 2) << 3) + (rho & 3);
        int swz = (rowm & 15) << 4;
        #pragma unroll
        for (int kc = 0; kc < 4; ++kc)
            qkOff[mb][kc] = rowm * 256 + ((kc * 64 + g * 16) ^ swz);
    }
    #pragma unroll
    for (int cb = 0; cb < 8; ++cb) {
        int c = cb * 16 + rho;
        int vswz = (c & 7) << 4;
        #pragma unroll
        for (int ks = 0; ks < 2; ++ks)
            pvOff[cb][ks] = c * 128 + ((ks * 64 + g * 16) ^ vswz);
    }

    char* const KB0 = lds;
    char* const KB1 = lds + 16384;
    char* const VB0 = lds + 32768;
    char* const VB1 = lds + 49152;
    const char* kG = xb  + (size_t)m_beg * 256;
    const char* vG = xtb + (size_t)m_beg * 2;

    auto stageK = [&](char* dst, int tile) {
        const char* s = kG + (size_t)tile * (64 * 256);
        #pragma unroll
        for (int k = 0; k < 4; ++k) gload_lds16(s + kOff[k], dst + (w * 4 + k) * 1024);
    };
    auto stageV = [&](char* dst, int tile) {
        const char* s = vG + (size_t)tile * (64 * 2);
        #pragma unroll
        for (int k = 0; k < 4; ++k) gload_lds16(s + vOff[k], dst + (w * 4 + k) * 1024);
    };

    f32x4 acc[2][8];
    #pragma unroll
    for (int tt = 0; tt < 2; ++tt)
        #pragma unroll
        for (int cb = 0; cb < 8; ++cb) acc[tt][cb] = (f32x4){0.f, 0.f, 0.f, 0.f};
    float m_run[2] = {-INFINITY, -INFINITY};
    float l_lane[2] = {0.f, 0.f};

    auto qkt = [&](const char* kb, f32x4 (&aS)[2][4]) {
        #pragma unroll
        for (int tt = 0; tt < 2; ++tt)
            #pragma unroll
            for (int mb = 0; mb < 4; ++mb) aS[tt][mb] = (f32x4){0.f, 0.f, 0.f, 0.f};
        #pragma unroll
        for (int mb = 0; mb < 4; ++mb)
            #pragma unroll
            for (int kc = 0; kc < 4; ++kc) {
                bf16x8 kf = *(const bf16x8*)(kb + qkOff[mb][kc]);
                aS[0][mb] = __builtin_amdgcn_mfma_f32_16x16x32_bf16(kf, qf[0][kc], aS[0][mb], 0, 0, 0);
                aS[1][mb] = __builtin_amdgcn_mfma_f32_16x16x32_bf16(kf, qf[1][kc], aS[1][mb], 0, 0, 0);
            }
    };

    auto smpv = [&](f32x4 (&aS)[2][4], const char* vb) {
        bf16x8 pb[2][2];
        #pragma unroll
        for (int tt = 0; tt < 2; ++tt) {
            float tm = aS[tt][0][0];
            #pragma unroll
            for (int mb = 0; mb < 4; ++mb)
                #pragma unroll
                for (int r = 0; r < 4; ++r) tm = fmaxf(tm, aS[tt][mb][r]);
            tm = fmaxf(tm, __shfl_xor(tm, 16));
            tm = fmaxf(tm, __shfl_xor(tm, 32));
            if (!__all(tm <= m_run[tt] + 6.0f)) {
                float nm = fmaxf(m_run[tt], tm);
                float sc = ex2(m_run[tt] - nm);
                l_lane[tt] *= sc;
                m_run[tt] = nm;
                #pragma unroll
                for (int cb = 0; cb < 8; ++cb) {
                    acc[tt][cb][0] *= sc; acc[tt][cb][1] *= sc;
                    acc[tt][cb][2] *= sc; acc[tt][cb][3] *= sc;
                }
            }
            float p[4][4];
            #pragma unroll
            for (int mb = 0; mb < 4; ++mb)
                #pragma unroll
                for (int r = 0; r < 4; ++r) {
                    p[mb][r] = ex2(aS[tt][mb][r] - m_run[tt]);
                    l_lane[tt] += p[mb][r];
                }
            #pragma unroll
            for (int ks = 0; ks < 2; ++ks) {
                union { bf16x8 v; unsigned int u[4]; } pk;
                pk.u[0] = pkbf(p[2 * ks][0],     p[2 * ks][1]);
                pk.u[1] = pkbf(p[2 * ks][2],     p[2 * ks][3]);
                pk.u[2] = pkbf(p[2 * ks + 1][0], p[2 * ks + 1][1]);
                pk.u[3] = pkbf(p[2 * ks + 1][2], p[2 * ks + 1][3]);
                pb[tt][ks] = pk.v;
            }
        }
        #pragma unroll
        for (int cb = 0; cb < 8; ++cb)
            #pragma unroll
            for (int ks = 0; ks < 2; ++ks) {
                bf16x8 vf = *(const bf16x8*)(vb + pvOff[cb][ks]);
                acc[0][cb] = __builtin_amdgcn_mfma_f32_16x16x32_bf16(vf, pb[0][ks], acc[0][cb], 0, 0, 0);
                acc[1][cb] = __builtin_amdgcn_mfma_f32_16x16x32_bf16(vf, pb[1][ks], acc[1][cb], 0, 0, 0);
            }
    };

    f32x4 accA[2][4], accB[2][4];

    stageK(KB0, 0); stageV(VB0, 0); stageK(KB1, 1); stageV(VB1, 1);
    asm volatile("s_waitcnt vmcnt(12)" ::: "memory");
    __builtin_amdgcn_s_barrier();
    qkt(KB0, accA);
    __builtin_amdgcn_s_barrier();
    if constexpr (NT > 2) stageK(KB0, 2);

    #pragma unroll 1
    for (int j = 0; j + 3 < NT; j += 2) {
        asm volatile("s_waitcnt vmcnt(8)" ::: "memory");
        __builtin_amdgcn_s_barrier();
        qkt(KB1, accB);
        smpv(accA, VB0);
        __builtin_amdgcn_s_barrier();
        stageK(KB1, j + 3);
        stageV(VB0, j + 2);
        asm volatile("s_waitcnt vmcnt(8)" ::: "memory");
        __builtin_amdgcn_s_barrier();
        qkt(KB0, accA);
        smpv(accB, VB1);
        __builtin_amdgcn_s_barrier();
        if (j + 4 < NT) stageK(KB0, j + 4);
        stageV(VB1, j + 3);
    }
    asm volatile("s_waitcnt vmcnt(4)" ::: "memory");
    __builtin_amdgcn_s_barrier();
    qkt(KB1, accB);
    smpv(accA, VB0);
    asm volatile("s_waitcnt vmcnt(0)" ::: "memory");
    __builtin_amdgcn_s_barrier();
    smpv(accB, VB1);

    #pragma unroll
    for (int tt = 0; tt < 2; ++tt) {
        l_lane[tt] += __shfl_xor(l_lane[tt], 16);
        l_lane[tt] += __shfl_xor(l_lane[tt], 32);
        const int n = n0 + w * 32 + tt * 16 + rho;
        #pragma unroll
        for (int cb = 0; cb < 8; ++cb)
            #pragma unroll
            for (int r = 0; r < 4; ++r)
                op[((size_t)(split * B_ + b) * C_ + cb * 16 + g * 4 + r) * N + n] = f2bf(acc[tt][cb][r]);
        if (g == 0) {
            ml[((size_t)(split * B_ + b) * N + n) * 2 + 0] = m_run[tt];
            ml[((size_t)(split * B_ + b) * N + n) * 2 + 1] = l_lane[tt];
        }
    }
}

// ONE launch for all three scales. ATTN1 FIRST (bid 0..511 = exactly full
// 2-blocks/CU residency, all start at t=0 and finish together); short smalls
// (512..783) run in the freed slots afterwards — avoids displacing attn1
// starts (r16's smalls-first cost the displaced blocks a late start).
__global__ __launch_bounds__(256, 2) void attn_fused(const unsigned short* __restrict__ xt1,
                                                     const unsigned short* __restrict__ xtT1,
                                                     unsigned short* __restrict__ o1p,
                                                     float* __restrict__ ml1,
                                                     const unsigned short* __restrict__ xt2,
                                                     const unsigned short* __restrict__ xtT2,
                                                     unsigned short* __restrict__ a2p,
                                                     float* __restrict__ ml2,
                                                     const unsigned short* __restrict__ xt4,
                                                     const unsigned short* __restrict__ xtT4,
                                                     unsigned short* __restrict__ a4p,
                                                     float* __restrict__ ml4) {
    __shared__ char lds[65536];
    const int bid = (int)blockIdx.x;
    if (bid < 512)
        attn_body<4096, 4>(xt1, xtT1, o1p, ml1, bid, lds);
    else if (bid < 768)
        attn_body<1024, 8>(xt2, xtT2, a2p, ml2, bid - 512, lds);
    else
        attn_body<256, 2>(xt4, xtT4, a4p, ml4, bid - 768, lds);
}

// ---------------- fused merge + upsample + scale-1 merge (r16, proven).
__global__ __launch_bounds__(256) void combine2(float* __restrict__ out,
                                                const unsigned short* __restrict__ o1p,
                                                const float* __restrict__ ml1,
                                                const unsigned short* __restrict__ a2p,
                                                const float* __restrict__ ml2,
                                                const unsigned short* __restrict__ a4p,
                                                const float* __restrict__ ml4) {
    __shared__ float a2s[1024];
    __shared__ float a4s[256];
    const int bc = (int)blockIdx.x;
    const int b  = bc >> 7;
    const int c  = bc & 127;
    const int t  = threadIdx.x;

    #pragma unroll
    for (int i = 0; i < 4; ++i) {
        int n = i * 256 + t;
        float M = -INFINITY;
        #pragma unroll
        for (int s = 0; s < 8; ++s) M = fmaxf(M, ml2[((s * 4 + b) * 1024 + n) * 2]);
        float L = 0.f, O = 0.f;
        #pragma unroll
        for (int s = 0; s < 8; ++s) {
            float wgt = ex2(ml2[((s * 4 + b) * 1024 + n) * 2] - M);
            L += ml2[((s * 4 + b) * 1024 + n) * 2 + 1] * wgt;
            O += bf2f(a2p[((size_t)((s * 4 + b) * 128 + c)) * 1024 + n]) * wgt;
        }
        a2s[n] = O / L;
    }
    {
        int n = t;
        float m0 = ml4[((0 * 4 + b) * 256 + n) * 2], l0 = ml4[((0 * 4 + b) * 256 + n) * 2 + 1];
        float m1 = ml4[((1 * 4 + b) * 256 + n) * 2], l1 = ml4[((1 * 4 + b) * 256 + n) * 2 + 1];
        float M  = fmaxf(m0, m1);
        float w0 = ex2(m0 - M), w1 = ex2(m1 - M);
        float O  = bf2f(a4p[((size_t)((0 * 4 + b) * 128 + c)) * 256 + n]) * w0
                 + bf2f(a4p[((size_t)((1 * 4 + b) * 128 + c)) * 256 + n]) * w1;
        a4s[n] = O / (l0 * w0 + l1 * w1);
    }
    __syncthreads();

    #pragma unroll
    for (int i = 0; i < 16; ++i) {
        int e = i * 256 + t;
        int h = e >> 6, w = e & 63;
        float M = -INFINITY;
        #pragma unroll
        for (int s = 0; s < 4; ++s) M = fmaxf(M, ml1[((size_t)(s * 4 + b) * 4096 + e) * 2]);
        float num = 0.f, den = 0.f;
        #pragma unroll
        for (int s = 0; s < 4; ++s) {
            float wgt = ex2(ml1[((size_t)(s * 4 + b) * 4096 + e) * 2] - M);
            den += ml1[((size_t)(s * 4 + b) * 4096 + e) * 2 + 1] * wgt;
            num += bf2f(o1p[((size_t)(s * 512 + bc)) * 4096 + e]) * wgt;
        }
        float v = num / den;
        {
            float sh = (h + 0.5f) * 0.5f - 0.5f;
            float sw = (w + 0.5f) * 0.5f - 0.5f;
            int h0 = (int)floorf(sh); float fh = sh - (float)h0;
            int w0 = (int)floorf(sw); float fw = sw - (float)w0;
            int h0c = max(h0, 0), h1c = min(h0 + 1, 31);
            int w0c = max(w0, 0), w1c = min(w0 + 1, 31);
            float v00 = a2s[h0c * 32 + w0c], v01 = a2s[h0c * 32 + w1c];
            float v10 = a2s[h1c * 32 + w0c], v11 = a2s[h1c * 32 + w1c];
            v += (1.f - fh) * ((1.f - fw) * v00 + fw * v01)
               +        fh  * ((1.f - fw) * v10 + fw * v11);
        }
        {
            float sh = (h + 0.5f) * 0.25f - 0.5f;
            float sw = (w + 0.5f) * 0.25f - 0.5f;
            int h0 = (int)floorf(sh); float fh = sh - (float)h0;
            int w0 = (int)floorf(sw); float fw = sw - (float)w0;
            int h0c = max(h0, 0), h1c = min(h0 + 1, 15);
            int w0c = max(w0, 0), w1c = min(w0 + 1, 15);
            float v00 = a4s[h0c * 16 + w0c], v01 = a4s[h0c * 16 + w1c];
            float v10 = a4s[h1c * 16 + w0c], v11 = a4s[h1c * 16 + w1c];
            v += (1.f - fh) * ((1.f - fw) * v00 + fw * v01)
               +        fh  * ((1.f - fw) * v10 + fw * v11);
        }
        out[(size_t)bc * 4096 + e] = v;
    }
}

extern "C" void kernel_launch(void* const* d_in, const int* in_sizes, int n_in,
                              void* d_out, int out_size, void* d_ws, size_t ws_size,
                              hipStream_t stream) {
    const float* x = (const float*)d_in[0];
    float* out = (float*)d_out;
    char* ws = (char*)d_ws;
    unsigned short* xt1  = (unsigned short*)(ws + XT1_B);
    unsigned short* xtT1 = (unsigned short*)(ws + XTT1_B);
    unsigned short* o1p  = (unsigned short*)(ws + O1P_B);
    float*          ml1  = (float*)(ws + ML1_B);
    unsigned short* xt2  = (unsigned short*)(ws + XT2_B);
    unsigned short* xtT2 = (unsigned short*)(ws + XTT2_B);
    unsigned short* xt4  = (unsigned short*)(ws + XT4_B);
    unsigned short* xtT4 = (unsigned short*)(ws + XTT4_B);
    unsigned short* a2p  = (unsigned short*)(ws + A2P_B);
    float*          ml2  = (float*)(ws + ML2_B);
    unsigned short* a4p  = (unsigned short*)(ws + A4P_B);
    float*          ml4  = (float*)(ws + ML4_B);

    pool_all<<<dim3(16, 4, B_), 256, 0, stream>>>(x, xt1, xtT1, xt2, xtT2, xt4, xtT4);
    attn_fused<<<784, 256, 0, stream>>>(xt1, xtT1, o1p, ml1,
                                        xt2, xtT2, a2p, ml2,
                                        xt4, xtT4, a4p, ml4);
    combine2<<<512, 256, 0, stream>>>(out, o1p, ml1, a2p, ml2, a4p, ml4);
}

// Round 19
// 73.500 us; speedup vs baseline: 1.0706x; 1.0208x over previous
//
#include <hip/hip_runtime.h>
#include <hip/hip_bf16.h>
#include <math.h>

typedef __attribute__((ext_vector_type(8))) short bf16x8;
typedef __attribute__((ext_vector_type(4))) float f32x4;

#define B_ 4
#define C_ 128
#define SQRT_LOG2E 1.2011224087864498f   // xt pre-scaled by this (Q and K each) => S carries log2e

// ---- workspace layout (r16/r18, proven) ----
#define XT1_B   0ull                      // 4 MB
#define XTT1_B  4194304ull                // 4 MB
#define O1P_B   8388608ull                // bf16 [4][4][128][4096]  16 MB
#define ML1_B   25165824ull               // f32  [4][4][4096][2]    512 KB
#define TAIL_B  25690112ull
#define XT2_B   (TAIL_B + 0ull)           // bf16 [4][1024][128]     1 MB
#define XTT2_B  (TAIL_B + 1048576ull)     // bf16 [4][128][1024]     1 MB
#define XT4_B   (TAIL_B + 2097152ull)     // bf16 [4][256][128]      256 KB
#define XTT4_B  (TAIL_B + 2359296ull)     // bf16 [4][128][256]      256 KB
#define A2P_B   (TAIL_B + 2621440ull)     // bf16 [8][4][128][1024]  8 MB
#define ML2_B   (TAIL_B + 11010048ull)    // f32  [8][4][1024][2]    256 KB
#define A4P_B   (TAIL_B + 11272192ull)    // bf16 [2][4][128][256]   512 KB
#define ML4_B   (TAIL_B + 11796480ull)    // f32  [2][4][256][2]     16 KB
// total = 37,502,976 B (ws >= 44.3 MB proven in r9/r12)

__device__ __forceinline__ float ex2(float x) { return __builtin_amdgcn_exp2f(x); }

__device__ __forceinline__ unsigned short f2bf(float f) {
    unsigned int u = __builtin_bit_cast(unsigned int, f);
    return (unsigned short)((u + 0x7FFFu + ((u >> 16) & 1u)) >> 16);
}
__device__ __forceinline__ float bf2f(unsigned short u) {
    unsigned int x = ((unsigned int)u) << 16;
    return __builtin_bit_cast(float, x);
}
__device__ __forceinline__ unsigned int pkbf(float lo, float hi) {
    union { __hip_bfloat162 h; unsigned int u; } c;
    c.h = __float22bfloat162_rn(make_float2(lo, hi));   // v_cvt_pk_bf16_f32
    return c.u;
}
__device__ __forceinline__ void gload_lds16(const void* g, void* l) {
    __builtin_amdgcn_global_load_lds(
        (const __attribute__((address_space(1))) unsigned int*)g,
        (__attribute__((address_space(3))) unsigned int*)l, 16, 0, 0);
}

// ---------------- fused pool: x[B][C][64][64] -> {xt,xtT} for scales 1,2,4.
// xt (Q/K) pre-scaled by sqrt(log2e); xtT (V) unscaled.
__global__ __launch_bounds__(256) void pool_all(const float* __restrict__ x,
                                                unsigned short* __restrict__ xt1,
                                                unsigned short* __restrict__ xtT1,
                                                unsigned short* __restrict__ xt2,
                                                unsigned short* __restrict__ xtT2,
                                                unsigned short* __restrict__ xt4,
                                                unsigned short* __restrict__ xtT4) {
    constexpr int RS = 257;
    __shared__ float lds[32 * RS];
    const int hp4 = blockIdx.x;
    const int c0  = blockIdx.y * 32;
    const int b   = blockIdx.z;
    const int t   = threadIdx.x;

    #pragma unroll
    for (int i = 0; i < 8; ++i) {
        int e4 = (i * 256 + t) * 4;
        int ci = e4 >> 8, rem = e4 & 255;
        float4 v = *reinterpret_cast<const float4*>(
            &x[((size_t)(b * C_ + c0 + ci) * 64 + (hp4 * 4 + (rem >> 6))) * 64 + (rem & 63)]);
        *reinterpret_cast<float4*>(&lds[ci * RS + rem]) = v;
    }
    __syncthreads();

    // scale 1: xt scaled, xtT raw (pair-packed stores)
    #pragma unroll
    for (int i = 0; i < 16; ++i) {
        int p  = i * 256 + t;
        int c2 = p & 15;
        int pos = p >> 4;
        unsigned int v = pkbf(lds[(2 * c2) * RS + pos] * SQRT_LOG2E,
                              lds[(2 * c2 + 1) * RS + pos] * SQRT_LOG2E);
        *reinterpret_cast<unsigned int*>(
            &xt1[((size_t)b * 4096 + hp4 * 256 + pos) * C_ + c0 + 2 * c2]) = v;
    }
    #pragma unroll
    for (int i = 0; i < 16; ++i) {
        int p  = i * 256 + t;
        int p2 = p & 127;
        int ci = p >> 7;
        unsigned int v = pkbf(lds[ci * RS + 2 * p2], lds[ci * RS + 2 * p2 + 1]);
        *reinterpret_cast<unsigned int*>(
            &xtT1[((size_t)(b * C_ + c0 + ci)) * 4096 + hp4 * 256 + 2 * p2]) = v;
    }
    // scale 2
    #pragma unroll
    for (int i = 0; i < 8; ++i) {
        int v = i * 256 + t;
        int ci = v & 31, pz = v >> 5;
        int r2 = pz >> 5, w2 = pz & 31;
        float s = lds[ci * RS + (2*r2)*64 + 2*w2]     + lds[ci * RS + (2*r2)*64 + 2*w2 + 1]
                + lds[ci * RS + (2*r2+1)*64 + 2*w2]   + lds[ci * RS + (2*r2+1)*64 + 2*w2 + 1];
        xt2[((size_t)b * 1024 + (hp4*2 + r2)*32 + w2) * C_ + c0 + ci] = f2bf(s * 0.25f * SQRT_LOG2E);
    }
    #pragma unroll
    for (int i = 0; i < 8; ++i) {
        int v = i * 256 + t;
        int pz = v & 63, ci = v >> 6;
        int r2 = pz >> 5, w2 = pz & 31;
        float s = lds[ci * RS + (2*r2)*64 + 2*w2]     + lds[ci * RS + (2*r2)*64 + 2*w2 + 1]
                + lds[ci * RS + (2*r2+1)*64 + 2*w2]   + lds[ci * RS + (2*r2+1)*64 + 2*w2 + 1];
        xtT2[((size_t)(b * C_ + c0 + ci)) * 1024 + (hp4*2 + r2)*32 + w2] = f2bf(s * 0.25f);
    }
    // scale 4
    #pragma unroll
    for (int i = 0; i < 2; ++i) {
        int v = i * 256 + t;
        int ci = v & 31, w4 = v >> 5;
        float s = 0.f;
        #pragma unroll
        for (int r = 0; r < 4; ++r)
            #pragma unroll
            for (int j = 0; j < 4; ++j) s += lds[ci * RS + r*64 + w4*4 + j];
        xt4[((size_t)b * 256 + hp4*16 + w4) * C_ + c0 + ci] = f2bf(s * 0.0625f * SQRT_LOG2E);
    }
    #pragma unroll
    for (int i = 0; i < 2; ++i) {
        int v = i * 256 + t;
        int w4 = v & 15, ci = v >> 4;
        float s = 0.f;
        #pragma unroll
        for (int r = 0; r < 4; ++r)
            #pragma unroll
            for (int j = 0; j < 4; ++j) s += lds[ci * RS + r*64 + w4*4 + j];
        xtT4[((size_t)(b * C_ + c0 + ci)) * 256 + hp4*16 + w4] = f2bf(s * 0.0625f);
    }
}

// ---------------- MFMA flash attention body (r10/16/18, proven config).
// KVBLK=64, split K/V double buffers (4 x 16 KB), counted-vmcnt schedule.
// Q loads straight from pre-scaled xt (no per-block scaling pass).
template<int N, int SPLIT>
__device__ __forceinline__ void attn_body(const unsigned short* __restrict__ xt,
                                          const unsigned short* __restrict__ xtT,
                                          unsigned short* __restrict__ op,
                                          float* __restrict__ ml,
                                          const int bid, char* lds) {
    constexpr int LOG2S = (SPLIT == 2) ? 1 : ((SPLIT == 4) ? 2 : 3);
    constexpr int QB = N / 128;
    constexpr int W2 = QB * SPLIT / 2;
    constexpr int NT = N / SPLIT / 64;
    static_assert(NT >= 2 && (NT & 1) == 0, "even NT >= 2 required");
    const int xcd   = bid & 7;
    const int b     = xcd >> 1;                 // batch pinned to XCD pair (L2 locality)
    const int wi    = (xcd & 1) * W2 + (bid >> 3);
    const int split = wi & (SPLIT - 1);
    const int qx    = wi >> LOG2S;
    const int n0    = qx * 128;
    const int m_beg = split * (N / SPLIT);

    const int tid = threadIdx.x;
    const int w = tid >> 6, lane = tid & 63;
    const int g = lane >> 4, rho = lane & 15;

    const char* xb  = (const char*)(xt  + (size_t)b * N * C_);
    const char* xtb = (const char*)(xtT + (size_t)b * C_ * N);

    bf16x8 qf[2][4];
    #pragma unroll
    for (int tt = 0; tt < 2; ++tt) {
        const char* qr = xb + (size_t)(n0 + w * 32 + tt * 16 + rho) * 256;
        #pragma unroll
        for (int kc = 0; kc < 4; ++kc)
            qf[tt][kc] = *(const bf16x8*)(qr + kc * 64 + g * 16);
    }

    int kOff[4], vOff[4];
    #pragma unroll
    for (int k = 0; k < 4; ++k) {
        int D = (w * 4 + k) * 1024 + lane * 16;
        int row = D >> 8, colb = D & 255;
        kOff[k] = row * 256 + (colb ^ ((row & 15) << 4));
        int c = D >> 7, cb2 = D & 127;
        vOff[k] = c * (2 * N) + (cb2 ^ ((c & 7) << 4));
    }
    int qkOff[4][4], pvOff[8][2];
    #pragma unroll
    for (int mb = 0; mb < 4; ++mb) {
        int rowm = ((mb >> 1) << 5) + ((mb & 1) << 2) + ((rho >> 2) << 3) + (rho & 3);
        int swz = (rowm & 15) << 4;
        #pragma unroll
        for (int kc = 0; kc < 4; ++kc)
            qkOff[mb][kc] = rowm * 256 + ((kc * 64 + g * 16) ^ swz);
    }
    #pragma unroll
    for (int cb = 0; cb < 8; ++cb) {
        int c = cb * 16 + rho;
        int vswz = (c & 7) << 4;
        #pragma unroll
        for (int ks = 0; ks < 2; ++ks)
            pvOff[cb][ks] = c * 128 + ((ks * 64 + g * 16) ^ vswz);
    }

    char* const KB0 = lds;
    char* const KB1 = lds + 16384;
    char* const VB0 = lds + 32768;
    char* const VB1 = lds + 49152;
    const char* kG = xb  + (size_t)m_beg * 256;
    const char* vG = xtb + (size_t)m_beg * 2;

    auto stageK = [&](char* dst, int tile) {
        const char* s = kG + (size_t)tile * (64 * 256);
        #pragma unroll
        for (int k = 0; k < 4; ++k) gload_lds16(s + kOff[k], dst + (w * 4 + k) * 1024);
    };
    auto stageV = [&](char* dst, int tile) {
        const char* s = vG + (size_t)tile * (64 * 2);
        #pragma unroll
        for (int k = 0; k < 4; ++k) gload_lds16(s + vOff[k], dst + (w * 4 + k) * 1024);
    };

    f32x4 acc[2][8];
    #pragma unroll
    for (int tt = 0; tt < 2; ++tt)
        #pragma unroll
        for (int cb = 0; cb < 8; ++cb) acc[tt][cb] = (f32x4){0.f, 0.f, 0.f, 0.f};
    float m_run[2] = {-INFINITY, -INFINITY};
    float l_lane[2] = {0.f, 0.f};

    auto qkt = [&](const char* kb, f32x4 (&aS)[2][4]) {
        #pragma unroll
        for (int tt = 0; tt < 2; ++tt)
            #pragma unroll
            for (int mb = 0; mb < 4; ++mb) aS[tt][mb] = (f32x4){0.f, 0.f, 0.f, 0.f};
        #pragma unroll
        for (int mb = 0; mb < 4; ++mb)
            #pragma unroll
            for (int kc = 0; kc < 4; ++kc) {
                bf16x8 kf = *(const bf16x8*)(kb + qkOff[mb][kc]);
                aS[0][mb] = __builtin_amdgcn_mfma_f32_16x16x32_bf16(kf, qf[0][kc], aS[0][mb], 0, 0, 0);
                aS[1][mb] = __builtin_amdgcn_mfma_f32_16x16x32_bf16(kf, qf[1][kc], aS[1][mb], 0, 0, 0);
            }
    };

    auto smpv = [&](f32x4 (&aS)[2][4], const char* vb) {
        bf16x8 pb[2][2];
        #pragma unroll
        for (int tt = 0; tt < 2; ++tt) {
            float tm = aS[tt][0][0];
            #pragma unroll
            for (int mb = 0; mb < 4; ++mb)
                #pragma unroll
                for (int r = 0; r < 4; ++r) tm = fmaxf(tm, aS[tt][mb][r]);
            tm = fmaxf(tm, __shfl_xor(tm, 16));
            tm = fmaxf(tm, __shfl_xor(tm, 32));
            if (!__all(tm <= m_run[tt] + 14.0f)) {      // defer-max, tau=14
                float nm = fmaxf(m_run[tt], tm);
                float sc = ex2(m_run[tt] - nm);
                l_lane[tt] *= sc;
                m_run[tt] = nm;
                #pragma unroll
                for (int cb = 0; cb < 8; ++cb) {
                    acc[tt][cb][0] *= sc; acc[tt][cb][1] *= sc;
                    acc[tt][cb][2] *= sc; acc[tt][cb][3] *= sc;
                }
            }
            float p[4][4];
            #pragma unroll
            for (int mb = 0; mb < 4; ++mb)
                #pragma unroll
                for (int r = 0; r < 4; ++r) {
                    p[mb][r] = ex2(aS[tt][mb][r] - m_run[tt]);
                    l_lane[tt] += p[mb][r];
                }
            #pragma unroll
            for (int ks = 0; ks < 2; ++ks) {
                union { bf16x8 v; unsigned int u[4]; } pk;
                pk.u[0] = pkbf(p[2 * ks][0],     p[2 * ks][1]);
                pk.u[1] = pkbf(p[2 * ks][2],     p[2 * ks][3]);
                pk.u[2] = pkbf(p[2 * ks + 1][0], p[2 * ks + 1][1]);
                pk.u[3] = pkbf(p[2 * ks + 1][2], p[2 * ks + 1][3]);
                pb[tt][ks] = pk.v;
            }
        }
        #pragma unroll
        for (int cb = 0; cb < 8; ++cb)
            #pragma unroll
            for (int ks = 0; ks < 2; ++ks) {
                bf16x8 vf = *(const bf16x8*)(vb + pvOff[cb][ks]);
                acc[0][cb] = __builtin_amdgcn_mfma_f32_16x16x32_bf16(vf, pb[0][ks], acc[0][cb], 0, 0, 0);
                acc[1][cb] = __builtin_amdgcn_mfma_f32_16x16x32_bf16(vf, pb[1][ks], acc[1][cb], 0, 0, 0);
            }
    };

    f32x4 accA[2][4], accB[2][4];

    stageK(KB0, 0); stageV(VB0, 0); stageK(KB1, 1); stageV(VB1, 1);
    asm volatile("s_waitcnt vmcnt(12)" ::: "memory");
    __builtin_amdgcn_s_barrier();
    qkt(KB0, accA);
    __builtin_amdgcn_s_barrier();
    if constexpr (NT > 2) stageK(KB0, 2);

    #pragma unroll 1
    for (int j = 0; j + 3 < NT; j += 2) {
        asm volatile("s_waitcnt vmcnt(8)" ::: "memory");
        __builtin_amdgcn_s_barrier();
        qkt(KB1, accB);
        smpv(accA, VB0);
        __builtin_amdgcn_s_barrier();
        stageK(KB1, j + 3);
        stageV(VB0, j + 2);
        asm volatile("s_waitcnt vmcnt(8)" ::: "memory");
        __builtin_amdgcn_s_barrier();
        qkt(KB0, accA);
        smpv(accB, VB1);
        __builtin_amdgcn_s_barrier();
        if (j + 4 < NT) stageK(KB0, j + 4);
        stageV(VB1, j + 3);
    }
    asm volatile("s_waitcnt vmcnt(4)" ::: "memory");
    __builtin_amdgcn_s_barrier();
    qkt(KB1, accB);
    smpv(accA, VB0);
    asm volatile("s_waitcnt vmcnt(0)" ::: "memory");
    __builtin_amdgcn_s_barrier();
    smpv(accB, VB1);

    #pragma unroll
    for (int tt = 0; tt < 2; ++tt) {
        l_lane[tt] += __shfl_xor(l_lane[tt], 16);
        l_lane[tt] += __shfl_xor(l_lane[tt], 32);
        const int n = n0 + w * 32 + tt * 16 + rho;
        #pragma unroll
        for (int cb = 0; cb < 8; ++cb)
            #pragma unroll
            for (int r = 0; r < 4; ++r)
                op[((size_t)(split * B_ + b) * C_ + cb * 16 + g * 4 + r) * N + n] = f2bf(acc[tt][cb][r]);
        if (g == 0) {
            ml[((size_t)(split * B_ + b) * N + n) * 2 + 0] = m_run[tt];
            ml[((size_t)(split * B_ + b) * N + n) * 2 + 1] = l_lane[tt];
        }
    }
}

// ONE launch for all three scales (r18 ordering: attn1 first, short smalls after).
__global__ __launch_bounds__(256, 2) void attn_fused(const unsigned short* __restrict__ xt1,
                                                     const unsigned short* __restrict__ xtT1,
                                                     unsigned short* __restrict__ o1p,
                                                     float* __restrict__ ml1,
                                                     const unsigned short* __restrict__ xt2,
                                                     const unsigned short* __restrict__ xtT2,
                                                     unsigned short* __restrict__ a2p,
                                                     float* __restrict__ ml2,
                                                     const unsigned short* __restrict__ xt4,
                                                     const unsigned short* __restrict__ xtT4,
                                                     unsigned short* __restrict__ a4p,
                                                     float* __restrict__ ml4) {
    __shared__ char lds[65536];
    const int bid = (int)blockIdx.x;
    if (bid < 512)
        attn_body<4096, 4>(xt1, xtT1, o1p, ml1, bid, lds);
    else if (bid < 768)
        attn_body<1024, 8>(xt2, xtT2, a2p, ml2, bid - 512, lds);
    else
        attn_body<256, 2>(xt4, xtT4, a4p, ml4, bid - 768, lds);
}

// ---------------- fused merge + upsample + scale-1 merge (r16, proven).
__global__ __launch_bounds__(256) void combine2(float* __restrict__ out,
                                                const unsigned short* __restrict__ o1p,
                                                const float* __restrict__ ml1,
                                                const unsigned short* __restrict__ a2p,
                                                const float* __restrict__ ml2,
                                                const unsigned short* __restrict__ a4p,
                                                const float* __restrict__ ml4) {
    __shared__ float a2s[1024];
    __shared__ float a4s[256];
    const int bc = (int)blockIdx.x;
    const int b  = bc >> 7;
    const int c  = bc & 127;
    const int t  = threadIdx.x;

    #pragma unroll
    for (int i = 0; i < 4; ++i) {
        int n = i * 256 + t;
        float M = -INFINITY;
        #pragma unroll
        for (int s = 0; s < 8; ++s) M = fmaxf(M, ml2[((s * 4 + b) * 1024 + n) * 2]);
        float L = 0.f, O = 0.f;
        #pragma unroll
        for (int s = 0; s < 8; ++s) {
            float wgt = ex2(ml2[((s * 4 + b) * 1024 + n) * 2] - M);
            L += ml2[((s * 4 + b) * 1024 + n) * 2 + 1] * wgt;
            O += bf2f(a2p[((size_t)((s * 4 + b) * 128 + c)) * 1024 + n]) * wgt;
        }
        a2s[n] = O / L;
    }
    {
        int n = t;
        float m0 = ml4[((0 * 4 + b) * 256 + n) * 2], l0 = ml4[((0 * 4 + b) * 256 + n) * 2 + 1];
        float m1 = ml4[((1 * 4 + b) * 256 + n) * 2], l1 = ml4[((1 * 4 + b) * 256 + n) * 2 + 1];
        float M  = fmaxf(m0, m1);
        float w0 = ex2(m0 - M), w1 = ex2(m1 - M);
        float O  = bf2f(a4p[((size_t)((0 * 4 + b) * 128 + c)) * 256 + n]) * w0
                 + bf2f(a4p[((size_t)((1 * 4 + b) * 128 + c)) * 256 + n]) * w1;
        a4s[n] = O / (l0 * w0 + l1 * w1);
    }
    __syncthreads();

    #pragma unroll
    for (int i = 0; i < 16; ++i) {
        int e = i * 256 + t;
        int h = e >> 6, w = e & 63;
        float M = -INFINITY;
        #pragma unroll
        for (int s = 0; s < 4; ++s) M = fmaxf(M, ml1[((size_t)(s * 4 + b) * 4096 + e) * 2]);
        float num = 0.f, den = 0.f;
        #pragma unroll
        for (int s = 0; s < 4; ++s) {
            float wgt = ex2(ml1[((size_t)(s * 4 + b) * 4096 + e) * 2] - M);
            den += ml1[((size_t)(s * 4 + b) * 4096 + e) * 2 + 1] * wgt;
            num += bf2f(o1p[((size_t)(s * 512 + bc)) * 4096 + e]) * wgt;
        }
        float v = num / den;
        {
            float sh = (h + 0.5f) * 0.5f - 0.5f;
            float sw = (w + 0.5f) * 0.5f - 0.5f;
            int h0 = (int)floorf(sh); float fh = sh - (float)h0;
            int w0 = (int)floorf(sw); float fw = sw - (float)w0;
            int h0c = max(h0, 0), h1c = min(h0 + 1, 31);
            int w0c = max(w0, 0), w1c = min(w0 + 1, 31);
            float v00 = a2s[h0c * 32 + w0c], v01 = a2s[h0c * 32 + w1c];
            float v10 = a2s[h1c * 32 + w0c], v11 = a2s[h1c * 32 + w1c];
            v += (1.f - fh) * ((1.f - fw) * v00 + fw * v01)
               +        fh  * ((1.f - fw) * v10 + fw * v11);
        }
        {
            float sh = (h + 0.5f) * 0.25f - 0.5f;
            float sw = (w + 0.5f) * 0.25f - 0.5f;
            int h0 = (int)floorf(sh); float fh = sh - (float)h0;
            int w0 = (int)floorf(sw); float fw = sw - (float)w0;
            int h0c = max(h0, 0), h1c = min(h0 + 1, 15);
            int w0c = max(w0, 0), w1c = min(w0 + 1, 15);
            float v00 = a4s[h0c * 16 + w0c], v01 = a4s[h0c * 16 + w1c];
            float v10 = a4s[h1c * 16 + w0c], v11 = a4s[h1c * 16 + w1c];
            v += (1.f - fh) * ((1.f - fw) * v00 + fw * v01)
               +        fh  * ((1.f - fw) * v10 + fw * v11);
        }
        out[(size_t)bc * 4096 + e] = v;
    }
}

extern "C" void kernel_launch(void* const* d_in, const int* in_sizes, int n_in,
                              void* d_out, int out_size, void* d_ws, size_t ws_size,
                              hipStream_t stream) {
    const float* x = (const float*)d_in[0];
    float* out = (float*)d_out;
    char* ws = (char*)d_ws;
    unsigned short* xt1  = (unsigned short*)(ws + XT1_B);
    unsigned short* xtT1 = (unsigned short*)(ws + XTT1_B);
    unsigned short* o1p  = (unsigned short*)(ws + O1P_B);
    float*          ml1  = (float*)(ws + ML1_B);
    unsigned short* xt2  = (unsigned short*)(ws + XT2_B);
    unsigned short* xtT2 = (unsigned short*)(ws + XTT2_B);
    unsigned short* xt4  = (unsigned short*)(ws + XT4_B);
    unsigned short* xtT4 = (unsigned short*)(ws + XTT4_B);
    unsigned short* a2p  = (unsigned short*)(ws + A2P_B);
    float*          ml2  = (float*)(ws + ML2_B);
    unsigned short* a4p  = (unsigned short*)(ws + A4P_B);
    float*          ml4  = (float*)(ws + ML4_B);

    pool_all<<<dim3(16, 4, B_), 256, 0, stream>>>(x, xt1, xtT1, xt2, xtT2, xt4, xtT4);
    attn_fused<<<784, 256, 0, stream>>>(xt1, xtT1, o1p, ml1,
                                        xt2, xtT2, a2p, ml2,
                                        xt4, xtT4, a4p, ml4);
    combine2<<<512, 256, 0, stream>>>(out, o1p, ml1, a2p, ml2, a4p, ml4);
}

// Round 20
// 69.040 us; speedup vs baseline: 1.1398x; 1.0646x over previous
//
#include <hip/hip_runtime.h>
#include <hip/hip_bf16.h>
#include <math.h>

typedef __attribute__((ext_vector_type(8))) short bf16x8;
typedef __attribute__((ext_vector_type(4))) float f32x4;

#define B_ 4
#define C_ 128
#define SQRT_LOG2E 1.2011224087864498f   // xt pre-scaled (Q and K each) => S carries log2e

// ---- workspace layout ----
#define XT1_B   0ull                      // 4 MB
#define XTT1_B  4194304ull                // 4 MB
#define O1P_B   8388608ull                // bf16 [4][4][128][4096]  16 MB
#define ML1_B   25165824ull               // f32  [4][4][4096][2]    512 KB
#define TAIL_B  25690112ull
#define XT2_B   (TAIL_B + 0ull)           // bf16 [4][1024][128]     1 MB
#define XTT2_B  (TAIL_B + 1048576ull)     // bf16 [4][128][1024]     1 MB
#define XT4_B   (TAIL_B + 2097152ull)     // bf16 [4][256][128]      256 KB
#define XTT4_B  (TAIL_B + 2359296ull)     // bf16 [4][128][256]      256 KB
#define A2P_B   (TAIL_B + 2621440ull)     // bf16 [4][4][128][1024]  4 MB
#define ML2_B   (TAIL_B + 6815744ull)     // f32  [4][4][1024][2]    128 KB
#define A4P_B   (TAIL_B + 6946816ull)     // bf16 [2][4][128][256]   512 KB
#define ML4_B   (TAIL_B + 7471104ull)     // f32  [2][4][256][2]     16 KB
// total = TAIL_B + 7,487,488 = 33,177,600 B (ws >= 44.3 MB proven r9/r12)

__device__ __forceinline__ float ex2(float x) { return __builtin_amdgcn_exp2f(x); }

__device__ __forceinline__ unsigned short f2bf(float f) {
    unsigned int u = __builtin_bit_cast(unsigned int, f);
    return (unsigned short)((u + 0x7FFFu + ((u >> 16) & 1u)) >> 16);
}
__device__ __forceinline__ float bf2f(unsigned short u) {
    unsigned int x = ((unsigned int)u) << 16;
    return __builtin_bit_cast(float, x);
}
__device__ __forceinline__ unsigned int pkbf(float lo, float hi) {
    union { __hip_bfloat162 h; unsigned int u; } c;
    c.h = __float22bfloat162_rn(make_float2(lo, hi));   // v_cvt_pk_bf16_f32
    return c.u;
}
__device__ __forceinline__ void gload_lds16(const void* g, void* l) {
    __builtin_amdgcn_global_load_lds(
        (const __attribute__((address_space(1))) unsigned int*)g,
        (__attribute__((address_space(3))) unsigned int*)l, 16, 0, 0);
}

// ---------------- fused pool: x[B][C][64][64] -> {xt,xtT} for scales 1,2,4.
// xt (Q/K) pre-scaled by sqrt(log2e); xtT (V) unscaled.
__global__ __launch_bounds__(256) void pool_all(const float* __restrict__ x,
                                                unsigned short* __restrict__ xt1,
                                                unsigned short* __restrict__ xtT1,
                                                unsigned short* __restrict__ xt2,
                                                unsigned short* __restrict__ xtT2,
                                                unsigned short* __restrict__ xt4,
                                                unsigned short* __restrict__ xtT4) {
    constexpr int RS = 257;
    __shared__ float lds[32 * RS];
    const int hp4 = blockIdx.x;
    const int c0  = blockIdx.y * 32;
    const int b   = blockIdx.z;
    const int t   = threadIdx.x;

    #pragma unroll
    for (int i = 0; i < 8; ++i) {
        int e4 = (i * 256 + t) * 4;
        int ci = e4 >> 8, rem = e4 & 255;
        float4 v = *reinterpret_cast<const float4*>(
            &x[((size_t)(b * C_ + c0 + ci) * 64 + (hp4 * 4 + (rem >> 6))) * 64 + (rem & 63)]);
        *reinterpret_cast<float4*>(&lds[ci * RS + rem]) = v;
    }
    __syncthreads();

    #pragma unroll
    for (int i = 0; i < 16; ++i) {
        int p  = i * 256 + t;
        int c2 = p & 15;
        int pos = p >> 4;
        unsigned int v = pkbf(lds[(2 * c2) * RS + pos] * SQRT_LOG2E,
                              lds[(2 * c2 + 1) * RS + pos] * SQRT_LOG2E);
        *reinterpret_cast<unsigned int*>(
            &xt1[((size_t)b * 4096 + hp4 * 256 + pos) * C_ + c0 + 2 * c2]) = v;
    }
    #pragma unroll
    for (int i = 0; i < 16; ++i) {
        int p  = i * 256 + t;
        int p2 = p & 127;
        int ci = p >> 7;
        unsigned int v = pkbf(lds[ci * RS + 2 * p2], lds[ci * RS + 2 * p2 + 1]);
        *reinterpret_cast<unsigned int*>(
            &xtT1[((size_t)(b * C_ + c0 + ci)) * 4096 + hp4 * 256 + 2 * p2]) = v;
    }
    #pragma unroll
    for (int i = 0; i < 8; ++i) {
        int v = i * 256 + t;
        int ci = v & 31, pz = v >> 5;
        int r2 = pz >> 5, w2 = pz & 31;
        float s = lds[ci * RS + (2*r2)*64 + 2*w2]     + lds[ci * RS + (2*r2)*64 + 2*w2 + 1]
                + lds[ci * RS + (2*r2+1)*64 + 2*w2]   + lds[ci * RS + (2*r2+1)*64 + 2*w2 + 1];
        xt2[((size_t)b * 1024 + (hp4*2 + r2)*32 + w2) * C_ + c0 + ci] = f2bf(s * 0.25f * SQRT_LOG2E);
    }
    #pragma unroll
    for (int i = 0; i < 8; ++i) {
        int v = i * 256 + t;
        int pz = v & 63, ci = v >> 6;
        int r2 = pz >> 5, w2 = pz & 31;
        float s = lds[ci * RS + (2*r2)*64 + 2*w2]     + lds[ci * RS + (2*r2)*64 + 2*w2 + 1]
                + lds[ci * RS + (2*r2+1)*64 + 2*w2]   + lds[ci * RS + (2*r2+1)*64 + 2*w2 + 1];
        xtT2[((size_t)(b * C_ + c0 + ci)) * 1024 + (hp4*2 + r2)*32 + w2] = f2bf(s * 0.25f);
    }
    #pragma unroll
    for (int i = 0; i < 2; ++i) {
        int v = i * 256 + t;
        int ci = v & 31, w4 = v >> 5;
        float s = 0.f;
        #pragma unroll
        for (int r = 0; r < 4; ++r)
            #pragma unroll
            for (int j = 0; j < 4; ++j) s += lds[ci * RS + r*64 + w4*4 + j];
        xt4[((size_t)b * 256 + hp4*16 + w4) * C_ + c0 + ci] = f2bf(s * 0.0625f * SQRT_LOG2E);
    }
    #pragma unroll
    for (int i = 0; i < 2; ++i) {
        int v = i * 256 + t;
        int w4 = v & 15, ci = v >> 4;
        float s = 0.f;
        #pragma unroll
        for (int r = 0; r < 4; ++r)
            #pragma unroll
            for (int j = 0; j < 4; ++j) s += lds[ci * RS + r*64 + w4*4 + j];
        xtT4[((size_t)(b * C_ + c0 + ci)) * 256 + hp4*16 + w4] = f2bf(s * 0.0625f);
    }
}

// ---------------- MFMA flash attention body (r19, proven best).
template<int N, int SPLIT>
__device__ __forceinline__ void attn_body(const unsigned short* __restrict__ xt,
                                          const unsigned short* __restrict__ xtT,
                                          unsigned short* __restrict__ op,
                                          float* __restrict__ ml,
                                          const int bid, char* lds) {
    constexpr int LOG2S = (SPLIT == 2) ? 1 : ((SPLIT == 4) ? 2 : 3);
    constexpr int QB = N / 128;
    constexpr int W2 = QB * SPLIT / 2;
    constexpr int NT = N / SPLIT / 64;
    static_assert(NT >= 2 && (NT & 1) == 0, "even NT >= 2 required");
    const int xcd   = bid & 7;
    const int b     = xcd >> 1;                 // batch pinned to XCD pair (L2 locality)
    const int wi    = (xcd & 1) * W2 + (bid >> 3);
    const int split = wi & (SPLIT - 1);
    const int qx    = wi >> LOG2S;
    const int n0    = qx * 128;
    const int m_beg = split * (N / SPLIT);

    const int tid = threadIdx.x;
    const int w = tid >> 6, lane = tid & 63;
    const int g = lane >> 4, rho = lane & 15;

    const char* xb  = (const char*)(xt  + (size_t)b * N * C_);
    const char* xtb = (const char*)(xtT + (size_t)b * C_ * N);

    bf16x8 qf[2][4];
    #pragma unroll
    for (int tt = 0; tt < 2; ++tt) {
        const char* qr = xb + (size_t)(n0 + w * 32 + tt * 16 + rho) * 256;
        #pragma unroll
        for (int kc = 0; kc < 4; ++kc)
            qf[tt][kc] = *(const bf16x8*)(qr + kc * 64 + g * 16);
    }

    int kOff[4], vOff[4];
    #pragma unroll
    for (int k = 0; k < 4; ++k) {
        int D = (w * 4 + k) * 1024 + lane * 16;
        int row = D >> 8, colb = D & 255;
        kOff[k] = row * 256 + (colb ^ ((row & 15) << 4));
        int c = D >> 7, cb2 = D & 127;
        vOff[k] = c * (2 * N) + (cb2 ^ ((c & 7) << 4));
    }
    int qkOff[4][4], pvOff[8][2];
    #pragma unroll
    for (int mb = 0; mb < 4; ++mb) {
        int rowm = ((mb >> 1) << 5) + ((mb & 1) << 2) + ((rho >> 2) << 3) + (rho & 3);
        int swz = (rowm & 15) << 4;
        #pragma unroll
        for (int kc = 0; kc < 4; ++kc)
            qkOff[mb][kc] = rowm * 256 + ((kc * 64 + g * 16) ^ swz);
    }
    #pragma unroll
    for (int cb = 0; cb < 8; ++cb) {
        int c = cb * 16 + rho;
        int vswz = (c & 7) << 4;
        #pragma unroll
        for (int ks = 0; ks < 2; ++ks)
            pvOff[cb][ks] = c * 128 + ((ks * 64 + g * 16) ^ vswz);
    }

    char* const KB0 = lds;
    char* const KB1 = lds + 16384;
    char* const VB0 = lds + 32768;
    char* const VB1 = lds + 49152;
    const char* kG = xb  + (size_t)m_beg * 256;
    const char* vG = xtb + (size_t)m_beg * 2;

    auto stageK = [&](char* dst, int tile) {
        const char* s = kG + (size_t)tile * (64 * 256);
        #pragma unroll
        for (int k = 0; k < 4; ++k) gload_lds16(s + kOff[k], dst + (w * 4 + k) * 1024);
    };
    auto stageV = [&](char* dst, int tile) {
        const char* s = vG + (size_t)tile * (64 * 2);
        #pragma unroll
        for (int k = 0; k < 4; ++k) gload_lds16(s + vOff[k], dst + (w * 4 + k) * 1024);
    };

    f32x4 acc[2][8];
    #pragma unroll
    for (int tt = 0; tt < 2; ++tt)
        #pragma unroll
        for (int cb = 0; cb < 8; ++cb) acc[tt][cb] = (f32x4){0.f, 0.f, 0.f, 0.f};
    float m_run[2] = {-INFINITY, -INFINITY};
    float l_lane[2] = {0.f, 0.f};

    auto qkt = [&](const char* kb, f32x4 (&aS)[2][4]) {
        #pragma unroll
        for (int tt = 0; tt < 2; ++tt)
            #pragma unroll
            for (int mb = 0; mb < 4; ++mb) aS[tt][mb] = (f32x4){0.f, 0.f, 0.f, 0.f};
        #pragma unroll
        for (int mb = 0; mb < 4; ++mb)
            #pragma unroll
            for (int kc = 0; kc < 4; ++kc) {
                bf16x8 kf = *(const bf16x8*)(kb + qkOff[mb][kc]);
                aS[0][mb] = __builtin_amdgcn_mfma_f32_16x16x32_bf16(kf, qf[0][kc], aS[0][mb], 0, 0, 0);
                aS[1][mb] = __builtin_amdgcn_mfma_f32_16x16x32_bf16(kf, qf[1][kc], aS[1][mb], 0, 0, 0);
            }
    };

    auto smpv = [&](f32x4 (&aS)[2][4], const char* vb) {
        bf16x8 pb[2][2];
        #pragma unroll
        for (int tt = 0; tt < 2; ++tt) {
            float tm = aS[tt][0][0];
            #pragma unroll
            for (int mb = 0; mb < 4; ++mb)
                #pragma unroll
                for (int r = 0; r < 4; ++r) tm = fmaxf(tm, aS[tt][mb][r]);
            tm = fmaxf(tm, __shfl_xor(tm, 16));
            tm = fmaxf(tm, __shfl_xor(tm, 32));
            if (!__all(tm <= m_run[tt] + 14.0f)) {      // defer-max, tau=14
                float nm = fmaxf(m_run[tt], tm);
                float sc = ex2(m_run[tt] - nm);
                l_lane[tt] *= sc;
                m_run[tt] = nm;
                #pragma unroll
                for (int cb = 0; cb < 8; ++cb) {
                    acc[tt][cb][0] *= sc; acc[tt][cb][1] *= sc;
                    acc[tt][cb][2] *= sc; acc[tt][cb][3] *= sc;
                }
            }
            float p[4][4];
            #pragma unroll
            for (int mb = 0; mb < 4; ++mb)
                #pragma unroll
                for (int r = 0; r < 4; ++r) {
                    p[mb][r] = ex2(aS[tt][mb][r] - m_run[tt]);
                    l_lane[tt] += p[mb][r];
                }
            #pragma unroll
            for (int ks = 0; ks < 2; ++ks) {
                union { bf16x8 v; unsigned int u[4]; } pk;
                pk.u[0] = pkbf(p[2 * ks][0],     p[2 * ks][1]);
                pk.u[1] = pkbf(p[2 * ks][2],     p[2 * ks][3]);
                pk.u[2] = pkbf(p[2 * ks + 1][0], p[2 * ks + 1][1]);
                pk.u[3] = pkbf(p[2 * ks + 1][2], p[2 * ks + 1][3]);
                pb[tt][ks] = pk.v;
            }
        }
        #pragma unroll
        for (int cb = 0; cb < 8; ++cb)
            #pragma unroll
            for (int ks = 0; ks < 2; ++ks) {
                bf16x8 vf = *(const bf16x8*)(vb + pvOff[cb][ks]);
                acc[0][cb] = __builtin_amdgcn_mfma_f32_16x16x32_bf16(vf, pb[0][ks], acc[0][cb], 0, 0, 0);
                acc[1][cb] = __builtin_amdgcn_mfma_f32_16x16x32_bf16(vf, pb[1][ks], acc[1][cb], 0, 0, 0);
            }
    };

    f32x4 accA[2][4], accB[2][4];

    stageK(KB0, 0); stageV(VB0, 0); stageK(KB1, 1); stageV(VB1, 1);
    asm volatile("s_waitcnt vmcnt(12)" ::: "memory");
    __builtin_amdgcn_s_barrier();
    qkt(KB0, accA);
    __builtin_amdgcn_s_barrier();
    if constexpr (NT > 2) stageK(KB0, 2);

    #pragma unroll 1
    for (int j = 0; j + 3 < NT; j += 2) {
        asm volatile("s_waitcnt vmcnt(8)" ::: "memory");
        __builtin_amdgcn_s_barrier();
        qkt(KB1, accB);
        smpv(accA, VB0);
        __builtin_amdgcn_s_barrier();
        stageK(KB1, j + 3);
        stageV(VB0, j + 2);
        asm volatile("s_waitcnt vmcnt(8)" ::: "memory");
        __builtin_amdgcn_s_barrier();
        qkt(KB0, accA);
        smpv(accB, VB1);
        __builtin_amdgcn_s_barrier();
        if (j + 4 < NT) stageK(KB0, j + 4);
        stageV(VB1, j + 3);
    }
    asm volatile("s_waitcnt vmcnt(4)" ::: "memory");
    __builtin_amdgcn_s_barrier();
    qkt(KB1, accB);
    smpv(accA, VB0);
    asm volatile("s_waitcnt vmcnt(0)" ::: "memory");
    __builtin_amdgcn_s_barrier();
    smpv(accB, VB1);

    #pragma unroll
    for (int tt = 0; tt < 2; ++tt) {
        l_lane[tt] += __shfl_xor(l_lane[tt], 16);
        l_lane[tt] += __shfl_xor(l_lane[tt], 32);
        const int n = n0 + w * 32 + tt * 16 + rho;
        #pragma unroll
        for (int cb = 0; cb < 8; ++cb)
            #pragma unroll
            for (int r = 0; r < 4; ++r)
                op[((size_t)(split * B_ + b) * C_ + cb * 16 + g * 4 + r) * N + n] = f2bf(acc[tt][cb][r]);
        if (g == 0) {
            ml[((size_t)(split * B_ + b) * N + n) * 2 + 0] = m_run[tt];
            ml[((size_t)(split * B_ + b) * N + n) * 2 + 1] = l_lane[tt];
        }
    }
}

// ONE launch: attn1 first (bid 0..511), then scale-2 SPLIT=4 (512..639, NT=4 —
// half the prologues of r19's SPLIT=8 with similar slot-clear time), then scale-4.
__global__ __launch_bounds__(256, 2) void attn_fused(const unsigned short* __restrict__ xt1,
                                                     const unsigned short* __restrict__ xtT1,
                                                     unsigned short* __restrict__ o1p,
                                                     float* __restrict__ ml1,
                                                     const unsigned short* __restrict__ xt2,
                                                     const unsigned short* __restrict__ xtT2,
                                                     unsigned short* __restrict__ a2p,
                                                     float* __restrict__ ml2,
                                                     const unsigned short* __restrict__ xt4,
                                                     const unsigned short* __restrict__ xtT4,
                                                     unsigned short* __restrict__ a4p,
                                                     float* __restrict__ ml4) {
    __shared__ char lds[65536];
    const int bid = (int)blockIdx.x;
    if (bid < 512)
        attn_body<4096, 4>(xt1, xtT1, o1p, ml1, bid, lds);
    else if (bid < 640)
        attn_body<1024, 4>(xt2, xtT2, a2p, ml2, bid - 512, lds);
    else
        attn_body<256, 2>(xt4, xtT4, a4p, ml4, bid - 640, lds);
}

// ---------------- fused merge + upsample + scale-1 merge.
__global__ __launch_bounds__(256) void combine2(float* __restrict__ out,
                                                const unsigned short* __restrict__ o1p,
                                                const float* __restrict__ ml1,
                                                const unsigned short* __restrict__ a2p,
                                                const float* __restrict__ ml2,
                                                const unsigned short* __restrict__ a4p,
                                                const float* __restrict__ ml4) {
    __shared__ float a2s[1024];
    __shared__ float a4s[256];
    const int bc = (int)blockIdx.x;
    const int b  = bc >> 7;
    const int c  = bc & 127;
    const int t  = threadIdx.x;

    #pragma unroll
    for (int i = 0; i < 4; ++i) {
        int n = i * 256 + t;
        float M = -INFINITY;
        #pragma unroll
        for (int s = 0; s < 4; ++s) M = fmaxf(M, ml2[((s * 4 + b) * 1024 + n) * 2]);
        float L = 0.f, O = 0.f;
        #pragma unroll
        for (int s = 0; s < 4; ++s) {
            float wgt = ex2(ml2[((s * 4 + b) * 1024 + n) * 2] - M);
            L += ml2[((s * 4 + b) * 1024 + n) * 2 + 1] * wgt;
            O += bf2f(a2p[((size_t)((s * 4 + b) * 128 + c)) * 1024 + n]) * wgt;
        }
        a2s[n] = O / L;
    }
    {
        int n = t;
        float m0 = ml4[((0 * 4 + b) * 256 + n) * 2], l0 = ml4[((0 * 4 + b) * 256 + n) * 2 + 1];
        float m1 = ml4[((1 * 4 + b) * 256 + n) * 2], l1 = ml4[((1 * 4 + b) * 256 + n) * 2 + 1];
        float M  = fmaxf(m0, m1);
        float w0 = ex2(m0 - M), w1 = ex2(m1 - M);
        float O  = bf2f(a4p[((size_t)((0 * 4 + b) * 128 + c)) * 256 + n]) * w0
                 + bf2f(a4p[((size_t)((1 * 4 + b) * 128 + c)) * 256 + n]) * w1;
        a4s[n] = O / (l0 * w0 + l1 * w1);
    }
    __syncthreads();

    #pragma unroll
    for (int i = 0; i < 16; ++i) {
        int e = i * 256 + t;
        int h = e >> 6, w = e & 63;
        float M = -INFINITY;
        #pragma unroll
        for (int s = 0; s < 4; ++s) M = fmaxf(M, ml1[((size_t)(s * 4 + b) * 4096 + e) * 2]);
        float num = 0.f, den = 0.f;
        #pragma unroll
        for (int s = 0; s < 4; ++s) {
            float wgt = ex2(ml1[((size_t)(s * 4 + b) * 4096 + e) * 2] - M);
            den += ml1[((size_t)(s * 4 + b) * 4096 + e) * 2 + 1] * wgt;
            num += bf2f(o1p[((size_t)(s * 512 + bc)) * 4096 + e]) * wgt;
        }
        float v = num / den;
        {
            float sh = (h + 0.5f) * 0.5f - 0.5f;
            float sw = (w + 0.5f) * 0.5f - 0.5f;
            int h0 = (int)floorf(sh); float fh = sh - (float)h0;
            int w0 = (int)floorf(sw); float fw = sw - (float)w0;
            int h0c = max(h0, 0), h1c = min(h0 + 1, 31);
            int w0c = max(w0, 0), w1c = min(w0 + 1, 31);
            float v00 = a2s[h0c * 32 + w0c], v01 = a2s[h0c * 32 + w1c];
            float v10 = a2s[h1c * 32 + w0c], v11 = a2s[h1c * 32 + w1c];
            v += (1.f - fh) * ((1.f - fw) * v00 + fw * v01)
               +        fh  * ((1.f - fw) * v10 + fw * v11);
        }
        {
            float sh = (h + 0.5f) * 0.25f - 0.5f;
            float sw = (w + 0.5f) * 0.25f - 0.5f;
            int h0 = (int)floorf(sh); float fh = sh - (float)h0;
            int w0 = (int)floorf(sw); float fw = sw - (float)w0;
            int h0c = max(h0, 0), h1c = min(h0 + 1, 15);
            int w0c = max(w0, 0), w1c = min(w0 + 1, 15);
            float v00 = a4s[h0c * 16 + w0c], v01 = a4s[h0c * 16 + w1c];
            float v10 = a4s[h1c * 16 + w0c], v11 = a4s[h1c * 16 + w1c];
            v += (1.f - fh) * ((1.f - fw) * v00 + fw * v01)
               +        fh  * ((1.f - fw) * v10 + fw * v11);
        }
        out[(size_t)bc * 4096 + e] = v;
    }
}

extern "C" void kernel_launch(void* const* d_in, const int* in_sizes, int n_in,
                              void* d_out, int out_size, void* d_ws, size_t ws_size,
                              hipStream_t stream) {
    const float* x = (const float*)d_in[0];
    float* out = (float*)d_out;
    char* ws = (char*)d_ws;
    unsigned short* xt1  = (unsigned short*)(ws + XT1_B);
    unsigned short* xtT1 = (unsigned short*)(ws + XTT1_B);
    unsigned short* o1p  = (unsigned short*)(ws + O1P_B);
    float*          ml1  = (float*)(ws + ML1_B);
    unsigned short* xt2  = (unsigned short*)(ws + XT2_B);
    unsigned short* xtT2 = (unsigned short*)(ws + XTT2_B);
    unsigned short* xt4  = (unsigned short*)(ws + XT4_B);
    unsigned short* xtT4 = (unsigned short*)(ws + XTT4_B);
    unsigned short* a2p  = (unsigned short*)(ws + A2P_B);
    float*          ml2  = (float*)(ws + ML2_B);
    unsigned short* a4p  = (unsigned short*)(ws + A4P_B);
    float*          ml4  = (float*)(ws + ML4_B);

    pool_all<<<dim3(16, 4, B_), 256, 0, stream>>>(x, xt1, xtT1, xt2, xtT2, xt4, xtT4);
    attn_fused<<<656, 256, 0, stream>>>(xt1, xtT1, o1p, ml1,
                                        xt2, xtT2, a2p, ml2,
                                        xt4, xtT4, a4p, ml4);
    combine2<<<512, 256, 0, stream>>>(out, o1p, ml1, a2p, ml2, a4p, ml4);
}